// Round 1
// 306.259 us; speedup vs baseline: 1.0623x; 1.0623x over previous
//
#include <hip/hip_runtime.h>

#define DEVI __device__ __forceinline__

typedef __attribute__((ext_vector_type(8))) __bf16 bf16x8;
typedef __attribute__((ext_vector_type(4))) float f32x4;
typedef __attribute__((ext_vector_type(4))) unsigned short u16x4;
typedef __attribute__((ext_vector_type(8))) unsigned short u16x8;

static DEVI unsigned short f2bf(float f) {  // manual RNE (cold paths)
  unsigned int i = __float_as_uint(f);
  i += 0x7fffu + ((i >> 16) & 1u);
  return (unsigned short)(i >> 16);
}

static DEVI unsigned short f2bfh(float f) {  // native cvt
  union { __bf16 h; unsigned short u; } c;
  c.h = (__bf16)f;
  return c.u;
}

static DEVI float bf2f(unsigned short u) {
  return __uint_as_float((unsigned int)u << 16);
}

static DEVI f32x4 mfma16x16x32(bf16x8 a, bf16x8 b, f32x4 c) {
  return __builtin_amdgcn_mfma_f32_16x16x32_bf16(a, b, c, 0, 0, 0);
}

static DEVI void async_ld16(const void* g, void* lds) {
  __builtin_amdgcn_global_load_lds(
      (const __attribute__((address_space(1))) void*)g,
      (__attribute__((address_space(3))) void*)lds, 16, 0, 0);
}

// raw barrier: does NOT drain vmcnt (unlike __syncthreads) — essential for the
// counted-vmcnt pipeline. Compiler memory fences stop load reordering across.
static DEVI void wg_barrier() {
  __asm__ volatile("" ::: "memory");
  __builtin_amdgcn_s_barrier();
  __asm__ volatile("" ::: "memory");
}

// ============================================================================
// 256x256 / BK=64 / 8-wave / 8-phase GEMM core (T2+T3+T4+T5 per guide §5/§5.5)
//
// Replaces the m97-style 128²/BK=32 2-barrier core (measured ceiling ~620 TF;
// MfmaUtil 23% on k_ffn2). Schedule (per K-tile kt, buffer c=kt&1, 4 phases):
//   q1: ds_read A(qm=0) 8x + B(qn=0) 4x ; stage (kt+1, Ah1) -> buf c^1
//   q2: ds_read B(qn=1) 4x              ; stage (kt+2, Ah0) -> buf c
//   q3: ds_read A(qm=1) 8x              ; stage (kt+2, Bh0) -> buf c
//   q4: (register reuse only)           ; stage (kt+2, Bh1) -> buf c
// each phase: [reads+stage] barrier ; setprio(1) 16xMFMA setprio(0) ; barrier
// vmcnt(6) ONLY at end of q4 (3 half-tiles = 6 wave-loads in flight) ->
// guarantees tile kt+1 fully landed. Tail: vmcnt(0) for last 2 tiles.
// Region-free proof: a half staged at phase P was last ds_read at phase <=P-1,
// and the staging issue sits after that phase's end barrier.
//
// LDS swizzle (T2): linear [256][64] bf16 is a 16-way bank conflict on
// ds_read_b128 (row stride 128B). Fix: 16B-granule XOR involution
//   granule' = granule ^ (row & 7)
// applied on the GLOBAL source address at stage time (global_load_lds dest
// must stay linear, guide rule #21) and on the ds_read address. Same
// involution family as k_attn's proven K/V octet swizzle.
//
// Wave grid 2M x 4N, INTERLEAVED so each phase touches exactly one half-tile:
//   A rows: qm*128 + wm*16 + m*32 + lr   (qm = phase row-quadrant)
//   B cols: qn*128 + wn*16 + n*64 + lr
// Per-wave output 128x64 -> acc[8][4] f32x4 (128 VGPR). af 32 + bf 32 VGPR.
// ============================================================================
template <int OUT_MODE, bool RELU>  // 1: bf16+bias(+RELU); 2: QKV scatter; 3: bf16 raw
static DEVI void gemm256_core(const unsigned short* __restrict__ A, int lda,
                              const unsigned short* __restrict__ Bt, int ldb,
                              int m0, int n0, const float* __restrict__ bias,
                              void* __restrict__ Cp, int ldc,
                              const float* __restrict__ bq,
                              const float* __restrict__ bk,
                              const float* __restrict__ bv,
                              unsigned short* __restrict__ qo,
                              unsigned short* __restrict__ ko,
                              unsigned short* __restrict__ vo) {
  constexpr int NKT = 16;  // K = 1024 for all users
  __shared__ __align__(16) unsigned short As[2][16384];  // [buf][256*64]
  __shared__ __align__(16) unsigned short Bs[2][16384];

  const int tid = threadIdx.x;
  const int w = tid >> 6, l = tid & 63;
  const int lr = l & 15, lq = l >> 4;
  const int wm = w >> 2, wn = w & 3;

  // ---- staging constants: thread t covers granule (t&7) of row (t>>3) of a
  // 64-row issue; source col pre-swizzled by the involution (r&7 == (t>>3)&7).
  const int srow = tid >> 3;
  const int scol = ((tid & 7) ^ (srow & 7)) << 3;
  const unsigned short* sA = A + (size_t)(m0 + srow) * lda + scol;
  const unsigned short* sB = Bt + (size_t)(n0 + srow) * ldb + scol;
  unsigned short* dA = &As[0][0] + w * 512;  // wave-uniform; HW adds lane*16B
  unsigned short* dB = &Bs[0][0] + w * 512;

  auto stA = [&](int c, int h, int kb) {
    const unsigned short* s = sA + (size_t)h * 128 * lda + kb;
    unsigned short* d = dA + c * 16384 + h * 8192;
    async_ld16(s, d);
    async_ld16(s + (size_t)64 * lda, d + 4096);
  };
  auto stB = [&](int c, int h, int kb) {
    const unsigned short* s = sB + (size_t)h * 128 * ldb + kb;
    unsigned short* d = dB + c * 16384 + h * 8192;
    async_ld16(s, d);
    async_ld16(s + (size_t)64 * ldb, d + 4096);
  };

  // ---- prologue: tile0 {Ah0,Bh0,Bh1,Ah1}, tile1 {Ah0,Bh0,Bh1}  (7 halves)
  stA(0, 0, 0); stB(0, 0, 0); stB(0, 1, 0); stA(0, 1, 0);
  stA(1, 0, 64); stB(1, 0, 64); stB(1, 1, 64);

  f32x4 acc[8][4];
#pragma unroll
  for (int i = 0; i < 8; ++i)
#pragma unroll
    for (int j = 0; j < 4; ++j) acc[i][j] = (f32x4){0.f, 0.f, 0.f, 0.f};

  // ---- fragment-read constants (swizzled granule offsets, elements)
  const int frow = wm * 16 + lr;
  const int brow = wn * 16 + lr;
  const int g0 = (lq ^ (lr & 7)) << 3;        // k32=0
  const int g1 = ((4 + lq) ^ (lr & 7)) << 3;  // k32=1

  bf16x8 af[4][2], bf[2][2][2];

  auto mfma_quad = [&](int qm, int qn) {
    __builtin_amdgcn_s_setprio(1);
#pragma unroll
    for (int m = 0; m < 4; ++m)
#pragma unroll
      for (int n = 0; n < 2; ++n) {
        f32x4 t = acc[qm * 4 + m][qn * 2 + n];
        t = mfma16x16x32(af[m][0], bf[qn][n][0], t);
        t = mfma16x16x32(af[m][1], bf[qn][n][1], t);
        acc[qm * 4 + m][qn * 2 + n] = t;
      }
    __builtin_amdgcn_s_setprio(0);
  };

  asm volatile("s_waitcnt vmcnt(6)" ::: "memory");  // tile0 complete
  wg_barrier();

  for (int kt = 0; kt < NKT; ++kt) {
    const int c = kt & 1;
    const unsigned short* Ac = &As[c][0];
    const unsigned short* Bc = &Bs[c][0];
    const int kb1 = (kt + 1) * 64, kb2 = (kt + 2) * 64;

    // ---- q1: A(qm=0) + B(qn=0); stage (kt+1, Ah1)
#pragma unroll
    for (int m = 0; m < 4; ++m) {
      const unsigned short* p = Ac + (frow + m * 32) * 64;
      af[m][0] = *(const bf16x8*)(p + g0);
      af[m][1] = *(const bf16x8*)(p + g1);
    }
#pragma unroll
    for (int n = 0; n < 2; ++n) {
      const unsigned short* p = Bc + (brow + n * 64) * 64;
      bf[0][n][0] = *(const bf16x8*)(p + g0);
      bf[0][n][1] = *(const bf16x8*)(p + g1);
    }
    if (kt + 1 < NKT) stA(c ^ 1, 1, kb1);
    wg_barrier();
    mfma_quad(0, 0);
    wg_barrier();

    // ---- q2: B(qn=1); stage (kt+2, Ah0)  [Ah0 of buf c freed at q1]
#pragma unroll
    for (int n = 0; n < 2; ++n) {
      const unsigned short* p = Bc + (128 + brow + n * 64) * 64;
      bf[1][n][0] = *(const bf16x8*)(p + g0);
      bf[1][n][1] = *(const bf16x8*)(p + g1);
    }
    if (kt + 2 < NKT) stA(c, 0, kb2);
    wg_barrier();
    mfma_quad(0, 1);  // af reuse
    wg_barrier();

    // ---- q3: A(qm=1); stage (kt+2, Bh0)  [Bh0 freed at q1; bf[0] in regs]
#pragma unroll
    for (int m = 0; m < 4; ++m) {
      const unsigned short* p = Ac + (128 + frow + m * 32) * 64;
      af[m][0] = *(const bf16x8*)(p + g0);
      af[m][1] = *(const bf16x8*)(p + g1);
    }
    if (kt + 2 < NKT) stB(c, 0, kb2);
    wg_barrier();
    mfma_quad(1, 0);
    wg_barrier();

    // ---- q4: register-only MFMA; stage (kt+2, Bh1)  [Bh1 freed at q2]
    if (kt + 2 < NKT) stB(c, 1, kb2);
    wg_barrier();
    mfma_quad(1, 1);
    if (kt < NKT - 2)
      asm volatile("s_waitcnt vmcnt(6)" ::: "memory");  // tile kt+1 landed
    else
      asm volatile("s_waitcnt vmcnt(0)" ::: "memory");  // tail drain
    wg_barrier();
  }

  // ---- epilogue
#pragma unroll
  for (int qm = 0; qm < 2; ++qm)
#pragma unroll
    for (int m = 0; m < 4; ++m) {
      const int grow = m0 + qm * 128 + wm * 16 + m * 32 + lq * 4;
#pragma unroll
      for (int qn = 0; qn < 2; ++qn)
#pragma unroll
        for (int n = 0; n < 2; ++n) {
          const int gcol = n0 + qn * 128 + wn * 16 + n * 64 + lr;
          const f32x4 av = acc[qm * 4 + m][qn * 2 + n];
          if (OUT_MODE == 2) {
            const int which = gcol >> 10;
            const int h = (gcol >> 6) & 15;
            const int e = gcol & 63;
            const float* bp = (which == 0) ? bq : (which == 1) ? bk : bv;
            const float bvv = bp[gcol & 1023];
#pragma unroll
            for (int r = 0; r < 4; ++r) {
              const int row = grow + r;
              const int b_ = row >> 11, s_ = row & 2047;
              const size_t base = (size_t)((b_ << 4) + h) * 131072;
              const float val = av[r] + bvv;
              if (which == 0) {
                qo[base + (size_t)s_ * 64 + e] = f2bf(val);
              } else if (which == 1) {
                // K: fold softmax scale (1/8 * log2e) + XOR-octet swizzle
                const int o = e >> 3;
                const int pos = (((o ^ (s_ & 7)) << 3) | (e & 7));
                ko[base + (size_t)s_ * 64 + pos] = f2bf(val * 0.18033688011112f);
              } else {
                // V: attn layout [dh][2048], kappa-permuted + XOR-octet swz
                const int t = s_ >> 6, k64 = s_ & 63;
                const int kap = (k64 & 15) * 4 + (k64 >> 4);
                const int pos = (((kap >> 3) ^ (e & 7)) << 3) | (kap & 7);
                vo[base + (size_t)e * 2048 + t * 64 + pos] = f2bf(val);
              }
            }
          } else if (OUT_MODE == 3) {
#pragma unroll
            for (int r = 0; r < 4; ++r)
              ((unsigned short*)Cp)[(size_t)(grow + r) * ldc + gcol] =
                  f2bf(av[r]);
          } else {
            const float bvv = bias[gcol];
#pragma unroll
            for (int r = 0; r < 4; ++r) {
              float val = av[r] + bvv;
              if (RELU) val = fmaxf(val, 0.f);
              ((unsigned short*)Cp)[(size_t)(grow + r) * ldc + gcol] = f2bf(val);
            }
          }
        }
    }
}

// grids are 1 block/CU (128KB LDS); per-XCD rectangular tile chunks (T1).
__global__ __launch_bounds__(512, 2) void k_gemm_qkv(
    const unsigned short* __restrict__ xb, const unsigned short* __restrict__ Wt,
    const float* __restrict__ bq, const float* __restrict__ bk,
    const float* __restrict__ bv, unsigned short* __restrict__ qo,
    unsigned short* __restrict__ ko, unsigned short* __restrict__ vo) {
  // 192 blocks = 16 Mt x 12 Nt; 24/xcd as 4M x 6N rectangle
  const int bid = blockIdx.x;
  const int xcd = bid & 7, idx = bid >> 3;
  const int mt = (xcd >> 1) * 4 + idx / 6;
  const int nt = (xcd & 1) * 6 + idx % 6;
  gemm256_core<2, false>(xb, 1024, Wt, 1024, mt * 256, nt * 256, nullptr,
                         nullptr, 0, bq, bk, bv, qo, ko, vo);
}

__global__ __launch_bounds__(512, 2) void k_ffn1(
    const unsigned short* __restrict__ h1b, const unsigned short* __restrict__ W1t,
    const float* __restrict__ b1, unsigned short* __restrict__ f1) {
  // 256 blocks = 16 x 16; 32/xcd as 4M x 8N rectangle
  const int bid = blockIdx.x;
  const int xcd = bid & 7, idx = bid >> 3;
  const int mt = (xcd >> 1) * 4 + (idx >> 3);
  const int nt = (xcd & 1) * 8 + (idx & 7);
  gemm256_core<1, true>(h1b, 1024, W1t, 1024, mt * 256, nt * 256, b1, f1, 4096,
                        nullptr, nullptr, nullptr, nullptr, nullptr, nullptr);
}

// split-K=4: z covers k in [z*1024, z*1024+1024); partials at pbase + z*4M.
__global__ __launch_bounds__(512, 2) void k_ffn2(
    const unsigned short* __restrict__ f1, const unsigned short* __restrict__ W2t,
    unsigned short* __restrict__ pbase) {
  const int z = blockIdx.z;
  unsigned short* p = pbase + (size_t)z * 4194304;
  // 64 blocks/z = 16 Mt x 4 Nt; 8/xcd as 2M x 4N (2 A-panels + 4 B-panels = 3MB, L2-fit)
  const int bid = blockIdx.x;
  const int xcd = bid & 7, idx = bid >> 3;
  const int mt = xcd * 2 + (idx >> 2);
  const int nt = idx & 3;
  gemm256_core<3, false>(f1 + z * 1024, 4096, W2t + z * 1024, 4096, mt * 256,
                         nt * 256, nullptr, p, 1024, nullptr, nullptr, nullptr,
                         nullptr, nullptr, nullptr);
}

// ---------------- unified prep: x cvt + all weight transposes -------------
static DEVI void tr64(const float* __restrict__ s, int sld,
                      unsigned short* __restrict__ d, int dld) {
  __shared__ float t[64][65];
  const int tr = threadIdx.x >> 4;
  const int tc4 = (threadIdx.x & 15) * 4;
#pragma unroll
  for (int i = 0; i < 4; ++i) {
    f32x4 v = *(const f32x4*)(s + (size_t)(i * 16 + tr) * sld + tc4);
#pragma unroll
    for (int j = 0; j < 4; ++j) t[i * 16 + tr][tc4 + j] = v[j];
  }
  __syncthreads();
#pragma unroll
  for (int i = 0; i < 4; ++i) {
    const int c = i * 16 + tr;
    u16x4 pk;
#pragma unroll
    for (int j = 0; j < 4; ++j) pk[j] = f2bf(t[tc4 + j][c]);
    *(u16x4*)(d + (size_t)c * dld + tc4) = pk;
  }
}

// Flat grid 3840 blocks:
//   [0,1024)     x fp32 -> bf16 (16 elems/thread)
//   [1024,1792)  Wq/Wk/Wv [H][1024][64] -> wqkvt [3072][1024]
//   [1792,2816)  W1 [1024][4096]        -> w1t   [4096][1024]
//   [2816,3840)  W2 [4096][1024]        -> w2t   [1024][4096]
__global__ __launch_bounds__(256) void k_prep(
    const float* __restrict__ x, const float* __restrict__ Wq,
    const float* __restrict__ Wk, const float* __restrict__ Wv,
    const float* __restrict__ W1, const float* __restrict__ W2,
    unsigned short* __restrict__ xb, unsigned short* __restrict__ wqkvt,
    unsigned short* __restrict__ w1t, unsigned short* __restrict__ w2t) {
  const int bid = blockIdx.x;
  if (bid < 1024) {
    const size_t i0 = ((size_t)bid * 256 + threadIdx.x) * 16;
#pragma unroll
    for (int c = 0; c < 4; ++c) {
      f32x4 v = *(const f32x4*)(x + i0 + c * 4);
      u16x4 pk;
#pragma unroll
      for (int j = 0; j < 4; ++j) pk[j] = f2bf(v[j]);
      *(u16x4*)(xb + i0 + c * 4) = pk;
    }
  } else if (bid < 1792) {
    const int t = bid - 1024;
    const int bx = t & 15, by = t >> 4;  // by: 0..47
    const int which = by >> 4, h = by & 15;
    const float* W = (which == 0) ? Wq : (which == 1) ? Wk : Wv;
    const float* s = W + (size_t)h * 65536;
    unsigned short* d = wqkvt + (size_t)(which * 1024 + h * 64) * 1024;
    const int r0 = bx * 64;
    tr64(s + (size_t)r0 * 64, 64, d + r0, 1024);
  } else if (bid < 2816) {
    const int t = bid - 1792;
    const int bx = t & 15, by = t >> 4;  // R=1024, C=4096
    const int r0 = bx * 64, c0 = by * 64;
    tr64(W1 + (size_t)r0 * 4096 + c0, 4096, w1t + (size_t)c0 * 1024 + r0, 1024);
  } else {
    const int t = bid - 2816;
    const int bx = t & 63, by = t >> 6;  // R=4096, C=1024
    const int r0 = bx * 64, c0 = by * 64;
    tr64(W2 + (size_t)r0 * 1024 + c0, 1024, w2t + (size_t)c0 * 4096 + r0, 4096);
  }
}

// ---------------- flash attention (unmasked per reference bug) -------------
// No-max softmax (|score*scale| < ~4, exp2-safe). Scale pre-folded into K.
// 512 threads / 8 waves, 16 Q-rows per wave; async dbuf staging, 1 barrier.
// mha written bf16.
__global__ __launch_bounds__(512) void k_attn(
    const unsigned short* __restrict__ q, const unsigned short* __restrict__ ks,
    const unsigned short* __restrict__ vp, unsigned short* __restrict__ mha) {
  const int bid = blockIdx.x;
  const int bh = (bid & 7) * 4 + ((bid >> 3) >> 4);  // 4 bh per XCD (L2 locality)
  const int qt = (bid >> 3) & 15;
  const int b = bh >> 4, h = bh & 15;
  const int tid = threadIdx.x;
  const int w = tid >> 6, l = tid & 63;
  const int lr = l & 15, lq = l >> 4, l7 = lr & 7;

  __shared__ __align__(16) unsigned short Ks[2][64 * 64];  // swizzled [key][dh]
  __shared__ __align__(16) unsigned short Vt[2][64 * 64];  // swizzled [dh][kappa]
  __shared__ __align__(16) unsigned short Ps[8][16][72];   // per-wave P, padded

  const size_t bho = (size_t)bh * 131072;
  const int q0 = qt * 128 + w * 16;

  bf16x8 qf0, qf1;
  {
    const unsigned short* qp = q + bho + (size_t)(q0 + lr) * 64 + lq * 8;
    qf0 = *(const bf16x8*)qp;
    qf1 = *(const bf16x8*)(qp + 32);
  }

  f32x4 l_acc[4];
  f32x4 o[4];
#pragma unroll
  for (int i = 0; i < 4; ++i) {
    l_acc[i] = (f32x4){0.f, 0.f, 0.f, 0.f};
    o[i] = (f32x4){0.f, 0.f, 0.f, 0.f};
  }

  const unsigned short* kg = ks + bho;
  const unsigned short* vg = vp + bho;
  const int srow = l >> 3, scol = (l & 7) * 8;
  const int r0 = w * 8;

  async_ld16(kg + (size_t)(r0 + srow) * 64 + scol, &Ks[0][r0 * 64]);
  async_ld16(vg + (size_t)(r0 + srow) * 2048 + scol, &Vt[0][r0 * 64]);
  __syncthreads();

  for (int kt = 0; kt < 32; ++kt) {
    const int cur = kt & 1, nxt = cur ^ 1;
    if (kt + 1 < 32) {
      const int k1 = (kt + 1) * 64;
      async_ld16(kg + (size_t)(k1 + r0 + srow) * 64 + scol, &Ks[nxt][r0 * 64]);
      async_ld16(vg + (size_t)(r0 + srow) * 2048 + k1 + scol, &Vt[nxt][r0 * 64]);
    }

    bf16x8 kf[4][2];
#pragma unroll
    for (int ct = 0; ct < 4; ++ct)
#pragma unroll
      for (int hh = 0; hh < 2; ++hh)
        kf[ct][hh] = *(const bf16x8*)&Ks[cur][(ct * 16 + lr) * 64 +
                                             (((hh << 2) | lq) ^ l7) * 8];
    f32x4 s[4];
#pragma unroll
    for (int ct = 0; ct < 4; ++ct) {
      f32x4 t = {0.f, 0.f, 0.f, 0.f};
      t = mfma16x16x32(qf0, kf[ct][0], t);
      t = mfma16x16x32(qf1, kf[ct][1], t);
      s[ct] = t;
    }

#pragma unroll
    for (int r = 0; r < 4; ++r) {
      f32x4 pe;
#pragma unroll
      for (int ct = 0; ct < 4; ++ct)
        pe[ct] = __builtin_amdgcn_exp2f(s[ct][r]);
      l_acc[r] += pe;
      u16x4 pk;
#pragma unroll
      for (int ct = 0; ct < 4; ++ct) pk[ct] = f2bfh(pe[ct]);
      *(u16x4*)&Ps[w][lq * 4 + r][lr * 4] = pk;  // kappa = lr*4+ct
    }
    __asm__ volatile("" ::: "memory");

    bf16x8 vf[4][2];
#pragma unroll
    for (int dt = 0; dt < 4; ++dt)
#pragma unroll
      for (int hh = 0; hh < 2; ++hh)
        vf[dt][hh] = *(const bf16x8*)&Vt[cur][(dt * 16 + lr) * 64 +
                                             (((hh << 2) | lq) ^ l7) * 8];
    bf16x8 pf0 = *(const bf16x8*)&Ps[w][lr][lq * 8];
    bf16x8 pf1 = *(const bf16x8*)&Ps[w][lr][32 + lq * 8];
#pragma unroll
    for (int dt = 0; dt < 4; ++dt) {
      o[dt] = mfma16x16x32(pf0, vf[dt][0], o[dt]);
      o[dt] = mfma16x16x32(pf1, vf[dt][1], o[dt]);
    }
    __syncthreads();
  }

#pragma unroll
  for (int r = 0; r < 4; ++r) {
    f32x4 la = l_acc[r];
    float sd = la[0] + la[1] + la[2] + la[3];
    sd += __shfl_xor(sd, 1);
    sd += __shfl_xor(sd, 2);
    sd += __shfl_xor(sd, 4);
    sd += __shfl_xor(sd, 8);
    const float inv = 1.f / sd;
    unsigned short* op =
        mha + ((size_t)b * 2048 + q0 + lq * 4 + r) * 1024 + h * 64 + lr;
    op[0] = f2bfh(o[0][r] * inv);
    op[16] = f2bfh(o[1][r] * inv);
    op[32] = f2bfh(o[2][r] * inv);
    op[48] = f2bfh(o[3][r] * inv);
  }
}

// ---------------- fused residual-add + LayerNorm -> bf16 ----------------
// a fp32 (x), b bf16 (mha).
__global__ __launch_bounds__(256) void k_add_ln(const float* __restrict__ a,
                                                const unsigned short* __restrict__ b,
                                                const float* __restrict__ g,
                                                const float* __restrict__ be,
                                                unsigned short* __restrict__ outb) {
  const int row = blockIdx.x;
  const int tid = threadIdx.x;
  const size_t base = (size_t)row * 1024 + tid * 4;
  f32x4 va = *(const f32x4*)(a + base);
  u16x4 ub = *(const u16x4*)(b + base);
  f32x4 xx;
  float s = 0.f, q = 0.f;
#pragma unroll
  for (int i = 0; i < 4; ++i) {
    xx[i] = va[i] + bf2f(ub[i]);
    s += xx[i];
    q += xx[i] * xx[i];
  }
#pragma unroll
  for (int off = 1; off < 64; off <<= 1) {
    s += __shfl_xor(s, off);
    q += __shfl_xor(q, off);
  }
  __shared__ float ss[4], qs[4];
  const int w = tid >> 6;
  if ((tid & 63) == 0) { ss[w] = s; qs[w] = q; }
  __syncthreads();
  s = ss[0] + ss[1] + ss[2] + ss[3];
  q = qs[0] + qs[1] + qs[2] + qs[3];
  const float mean = s * (1.f / 1024.f);
  const float var = q * (1.f / 1024.f) - mean * mean;
  const float rstd = rsqrtf(var + 1e-5f);
  f32x4 vg = *(const f32x4*)(g + tid * 4);
  f32x4 vbe = *(const f32x4*)(be + tid * 4);
  u16x4 pk;
#pragma unroll
  for (int i = 0; i < 4; ++i)
    pk[i] = f2bf((xx[i] - mean) * rstd * vg[i] + vbe[i]);
  *(u16x4*)(outb + base) = pk;
}

// out = LN(h1b + p0..p3 + b2): ffn2 split-K=4 partials + bias + LN (fp32 out).
__global__ __launch_bounds__(256) void k_add_ln4(
    const unsigned short* __restrict__ h1b, const unsigned short* __restrict__ pb,
    const float* __restrict__ cb, const float* __restrict__ g,
    const float* __restrict__ be, float* __restrict__ out) {
  const int row = blockIdx.x;
  const int tid = threadIdx.x;
  const size_t base = (size_t)row * 1024 + tid * 4;
  u16x4 uh = *(const u16x4*)(h1b + base);
  u16x4 up[4];
#pragma unroll
  for (int z = 0; z < 4; ++z)
    up[z] = *(const u16x4*)(pb + base + (size_t)z * 4194304);
  f32x4 vcb = *(const f32x4*)(cb + tid * 4);
  f32x4 xx;
  float s = 0.f, q = 0.f;
#pragma unroll
  for (int i = 0; i < 4; ++i) {
    float v = bf2f(uh[i]) + vcb[i];
#pragma unroll
    for (int z = 0; z < 4; ++z) v += bf2f(up[z][i]);
    xx[i] = v;
    s += v;
    q += v * v;
  }
#pragma unroll
  for (int off = 1; off < 64; off <<= 1) {
    s += __shfl_xor(s, off);
    q += __shfl_xor(q, off);
  }
  __shared__ float ss[4], qs[4];
  const int w = tid >> 6;
  if ((tid & 63) == 0) { ss[w] = s; qs[w] = q; }
  __syncthreads();
  s = ss[0] + ss[1] + ss[2] + ss[3];
  q = qs[0] + qs[1] + qs[2] + qs[3];
  const float mean = s * (1.f / 1024.f);
  const float var = q * (1.f / 1024.f) - mean * mean;
  const float rstd = rsqrtf(var + 1e-5f);
  f32x4 vg = *(const f32x4*)(g + tid * 4);
  f32x4 vbe = *(const f32x4*)(be + tid * 4);
  f32x4 ov;
#pragma unroll
  for (int i = 0; i < 4; ++i) ov[i] = (xx[i] - mean) * rstd * vg[i] + vbe[i];
  *(f32x4*)(out + base) = ov;
}

// ---------------- host launcher ----------------
extern "C" void kernel_launch(void* const* d_in, const int* in_sizes, int n_in,
                              void* d_out, int out_size, void* d_ws,
                              size_t ws_size, hipStream_t stream) {
  const float* x = (const float*)d_in[0];
  // d_in[1] attention_mask: discarded by reference (typo bug) -> unused
  const float* Wq = (const float*)d_in[2];
  const float* bq = (const float*)d_in[3];
  const float* Wk = (const float*)d_in[4];
  const float* bk = (const float*)d_in[5];
  const float* Wv = (const float*)d_in[6];
  const float* bv = (const float*)d_in[7];
  const float* lg = (const float*)d_in[8];
  const float* lb = (const float*)d_in[9];
  const float* W1 = (const float*)d_in[10];
  const float* b1 = (const float*)d_in[11];
  const float* W2 = (const float*)d_in[12];
  const float* b2 = (const float*)d_in[13];

  char* ws = (char*)d_ws;
  const size_t MB = 1024 * 1024;
  // liveness-overlapped plan (peak 94 MB):
  unsigned short* qb = (unsigned short*)(ws + 0);          // 8MB [qkv -> attn]
  unsigned short* kb = (unsigned short*)(ws + 8 * MB);     // 8MB [qkv -> attn]
  unsigned short* vp = (unsigned short*)(ws + 16 * MB);    // 8MB [qkv -> attn]
  unsigned short* f1 = (unsigned short*)(ws + 0);          // 32MB [ffn1 -> ffn2]
  unsigned short* xb = (unsigned short*)(ws + 32 * MB);    // 8MB [prep -> qkv]
  unsigned short* pb = (unsigned short*)(ws + 32 * MB);    // 32MB [ffn2 -> ln4]
  unsigned short* mha = (unsigned short*)(ws + 40 * MB);   // 8MB bf16 [attn -> ln1]
  unsigned short* h1b = (unsigned short*)(ws + 64 * MB);   // 8MB [ln1 -> ffn1,ln4]
  unsigned short* wqkvt = (unsigned short*)(ws + 72 * MB); // 6MB [prep -> qkv]
  unsigned short* w1t = (unsigned short*)(ws + 78 * MB);   // 8MB [prep -> ffn1]
  unsigned short* w2t = (unsigned short*)(ws + 86 * MB);   // 8MB [prep -> ffn2]

  k_prep<<<dim3(3840), 256, 0, stream>>>(x, Wq, Wk, Wv, W1, W2, xb, wqkvt, w1t,
                                         w2t);
  k_gemm_qkv<<<dim3(192), 512, 0, stream>>>(xb, wqkvt, bq, bk, bv, qb, kb, vp);
  k_attn<<<dim3(512), 512, 0, stream>>>(qb, kb, vp, mha);
  k_add_ln<<<dim3(4096), 256, 0, stream>>>(x, mha, lg, lb, h1b);
  k_ffn1<<<dim3(256), 512, 0, stream>>>(h1b, w1t, b1, f1);
  k_ffn2<<<dim3(64, 1, 4), 512, 0, stream>>>(f1, w2t, pb);
  k_add_ln4<<<dim3(4096), 256, 0, stream>>>(h1b, pb, b2, lg, lb, (float*)d_out);
}

// Round 2
// 305.672 us; speedup vs baseline: 1.0644x; 1.0019x over previous
//
#include <hip/hip_runtime.h>

#define DEVI __device__ __forceinline__

typedef __attribute__((ext_vector_type(8))) __bf16 bf16x8;
typedef __attribute__((ext_vector_type(4))) float f32x4;
typedef __attribute__((ext_vector_type(4))) unsigned short u16x4;
typedef __attribute__((ext_vector_type(8))) unsigned short u16x8;

static DEVI unsigned short f2bf(float f) {  // manual RNE (cold paths)
  unsigned int i = __float_as_uint(f);
  i += 0x7fffu + ((i >> 16) & 1u);
  return (unsigned short)(i >> 16);
}

static DEVI unsigned short f2bfh(float f) {  // native cvt
  union { __bf16 h; unsigned short u; } c;
  c.h = (__bf16)f;
  return c.u;
}

static DEVI float bf2f(unsigned short u) {
  return __uint_as_float((unsigned int)u << 16);
}

static DEVI f32x4 mfma16x16x32(bf16x8 a, bf16x8 b, f32x4 c) {
  return __builtin_amdgcn_mfma_f32_16x16x32_bf16(a, b, c, 0, 0, 0);
}

static DEVI void async_ld16(const void* g, void* lds) {
  __builtin_amdgcn_global_load_lds(
      (const __attribute__((address_space(1))) void*)g,
      (__attribute__((address_space(3))) void*)lds, 16, 0, 0);
}

// ============================================================================
// 256x256 / BK=64 / 8-wave / 8-phase GEMM core (T2+T3+T4+T5 per guide §5/§5.5)
//
// R1 POST-MORTEM (423 TF, MfmaUtil 15.6%): the round-1 version wrapped every
// barrier in asm volatile(""::: "memory") and put "memory" clobbers on the
// waitcnt asms. mayLoad/mayStore inline asm makes the waitcnt-insertion pass
// conservatively FLUSH vmcnt before the asm -> full drain at all 8 barriers
// per K-tile -> counted vmcnt(6) dead, HBM latency exposed per phase (the
// exact drain0-vs-counted regime of m218, -38..-73%). FIX (this round): raw
// s_barrier + clobber-free waitcnt asms (template fidelity); ordering safety
// via LDS alias analysis (global_load_lds carries its LDS dest operand) +
// sched_barrier(0) fences after each lgkmcnt/vmcnt (rule #18, compile-time
// only). DO NOT reintroduce "memory" clobbers in this loop.
//
// Schedule (per K-tile kt, buffer c=kt&1, 4 phases):
//   q1: ds_read A(qm=0) 8x + B(qn=0) 4x ; stage (kt+1, Ah1) -> buf c^1
//   q2: ds_read B(qn=1) 4x              ; stage (kt+2, Ah0) -> buf c
//   q3: ds_read A(qm=1) 8x              ; stage (kt+2, Bh0) -> buf c
//   q4: (register reuse only)           ; stage (kt+2, Bh1) -> buf c
// each phase: [reads+stage] s_barrier ; lgkmcnt(0)+fence ; setprio(1)
//   16xMFMA setprio(0) ; s_barrier
// vmcnt(6) ONLY at end of q4 (3 half-tiles = 6 wave-loads in flight).
// Cross-wave safety: post-barrier lgkmcnt(0) means a wave passing the phase
// END barrier has completed its reads -> next phase may overwrite that half.
// The end-of-tile vmcnt(6)+barrier guarantees ALL waves' tile-(kt+1) stages
// landed before any wave reads buf c^1.
//
// LDS swizzle (T2): 16B-granule XOR involution granule' = granule ^ (row&7),
// applied on the GLOBAL source at stage time (linear LDS dest, rule #21) and
// on the ds_read address. Measured: SQ_LDS_BANK_CONFLICT = 0.
// ============================================================================
template <int OUT_MODE, bool RELU>  // 1: bf16+bias(+RELU); 2: QKV scatter; 3: bf16 raw
static DEVI void gemm256_core(const unsigned short* __restrict__ A, int lda,
                              const unsigned short* __restrict__ Bt, int ldb,
                              int m0, int n0, const float* __restrict__ bias,
                              void* __restrict__ Cp, int ldc,
                              const float* __restrict__ bq,
                              const float* __restrict__ bk,
                              const float* __restrict__ bv,
                              unsigned short* __restrict__ qo,
                              unsigned short* __restrict__ ko,
                              unsigned short* __restrict__ vo) {
  constexpr int NKT = 16;  // K = 1024 for all users
  __shared__ __align__(16) unsigned short As[2][16384];  // [buf][256*64]
  __shared__ __align__(16) unsigned short Bs[2][16384];

  const int tid = threadIdx.x;
  const int w = tid >> 6, l = tid & 63;
  const int lr = l & 15, lq = l >> 4;
  const int wm = w >> 2, wn = w & 3;

  // ---- staging constants: thread t covers granule (t&7) of row (t>>3) of a
  // 64-row issue; source col pre-swizzled by the involution (r&7 == (t>>3)&7).
  const int srow = tid >> 3;
  const int scol = ((tid & 7) ^ (srow & 7)) << 3;
  const unsigned short* sA = A + (size_t)(m0 + srow) * lda + scol;
  const unsigned short* sB = Bt + (size_t)(n0 + srow) * ldb + scol;
  unsigned short* dA = &As[0][0] + w * 512;  // wave-uniform; HW adds lane*16B
  unsigned short* dB = &Bs[0][0] + w * 512;

  auto stA = [&](int c, int h, int kb) {
    const unsigned short* s = sA + (size_t)h * 128 * lda + kb;
    unsigned short* d = dA + c * 16384 + h * 8192;
    async_ld16(s, d);
    async_ld16(s + (size_t)64 * lda, d + 4096);
  };
  auto stB = [&](int c, int h, int kb) {
    const unsigned short* s = sB + (size_t)h * 128 * ldb + kb;
    unsigned short* d = dB + c * 16384 + h * 8192;
    async_ld16(s, d);
    async_ld16(s + (size_t)64 * ldb, d + 4096);
  };

  // ---- prologue: tile0 {Ah0,Bh0,Bh1,Ah1}, tile1 {Ah0,Bh0,Bh1}  (7 halves)
  stA(0, 0, 0); stB(0, 0, 0); stB(0, 1, 0); stA(0, 1, 0);
  stA(1, 0, 64); stB(1, 0, 64); stB(1, 1, 64);

  f32x4 acc[8][4];
#pragma unroll
  for (int i = 0; i < 8; ++i)
#pragma unroll
    for (int j = 0; j < 4; ++j) acc[i][j] = (f32x4){0.f, 0.f, 0.f, 0.f};

  // ---- fragment-read constants (swizzled granule offsets, elements)
  const int frow = wm * 16 + lr;
  const int brow = wn * 16 + lr;
  const int g0 = (lq ^ (lr & 7)) << 3;        // k32=0
  const int g1 = ((4 + lq) ^ (lr & 7)) << 3;  // k32=1

  bf16x8 af[4][2], bf[2][2][2];

  auto mfma_quad = [&](int qm, int qn) {
    __builtin_amdgcn_s_setprio(1);
#pragma unroll
    for (int m = 0; m < 4; ++m)
#pragma unroll
      for (int n = 0; n < 2; ++n) {
        f32x4 t = acc[qm * 4 + m][qn * 2 + n];
        t = mfma16x16x32(af[m][0], bf[qn][n][0], t);
        t = mfma16x16x32(af[m][1], bf[qn][n][1], t);
        acc[qm * 4 + m][qn * 2 + n] = t;
      }
    __builtin_amdgcn_s_setprio(0);
  };

  asm volatile("s_waitcnt vmcnt(6)");  // tile0 complete (NO memory clobber)
  __builtin_amdgcn_sched_barrier(0);
  __builtin_amdgcn_s_barrier();

  for (int kt = 0; kt < NKT; ++kt) {
    __builtin_amdgcn_sched_barrier(0);  // pin: nothing crosses tile boundary
    const int c = kt & 1;
    const unsigned short* Ac = &As[c][0];
    const unsigned short* Bc = &Bs[c][0];
    const int kb1 = (kt + 1) * 64, kb2 = (kt + 2) * 64;

    // ---- q1: A(qm=0) + B(qn=0); stage (kt+1, Ah1)
#pragma unroll
    for (int m = 0; m < 4; ++m) {
      const unsigned short* p = Ac + (frow + m * 32) * 64;
      af[m][0] = *(const bf16x8*)(p + g0);
      af[m][1] = *(const bf16x8*)(p + g1);
    }
#pragma unroll
    for (int n = 0; n < 2; ++n) {
      const unsigned short* p = Bc + (brow + n * 64) * 64;
      bf[0][n][0] = *(const bf16x8*)(p + g0);
      bf[0][n][1] = *(const bf16x8*)(p + g1);
    }
    if (kt + 1 < NKT) stA(c ^ 1, 1, kb1);
    __builtin_amdgcn_s_barrier();
    asm volatile("s_waitcnt lgkmcnt(0)");
    __builtin_amdgcn_sched_barrier(0);
    mfma_quad(0, 0);
    __builtin_amdgcn_s_barrier();

    // ---- q2: B(qn=1); stage (kt+2, Ah0)  [Ah0 of buf c freed at q1]
#pragma unroll
    for (int n = 0; n < 2; ++n) {
      const unsigned short* p = Bc + (128 + brow + n * 64) * 64;
      bf[1][n][0] = *(const bf16x8*)(p + g0);
      bf[1][n][1] = *(const bf16x8*)(p + g1);
    }
    if (kt + 2 < NKT) stA(c, 0, kb2);
    __builtin_amdgcn_s_barrier();
    asm volatile("s_waitcnt lgkmcnt(0)");
    __builtin_amdgcn_sched_barrier(0);
    mfma_quad(0, 1);  // af reuse
    __builtin_amdgcn_s_barrier();

    // ---- q3: A(qm=1); stage (kt+2, Bh0)  [Bh0 freed at q1; bf[0] in regs]
#pragma unroll
    for (int m = 0; m < 4; ++m) {
      const unsigned short* p = Ac + (128 + frow + m * 32) * 64;
      af[m][0] = *(const bf16x8*)(p + g0);
      af[m][1] = *(const bf16x8*)(p + g1);
    }
    if (kt + 2 < NKT) stB(c, 0, kb2);
    __builtin_amdgcn_s_barrier();
    asm volatile("s_waitcnt lgkmcnt(0)");
    __builtin_amdgcn_sched_barrier(0);
    mfma_quad(1, 0);
    __builtin_amdgcn_s_barrier();

    // ---- q4: register-only MFMA; stage (kt+2, Bh1)  [Bh1 freed at q2]
    if (kt + 2 < NKT) stB(c, 1, kb2);
    __builtin_amdgcn_s_barrier();
    asm volatile("s_waitcnt lgkmcnt(0)");
    __builtin_amdgcn_sched_barrier(0);
    mfma_quad(1, 1);
    if (kt < NKT - 2)
      asm volatile("s_waitcnt vmcnt(6)");  // tile kt+1 landed (counted!)
    else
      asm volatile("s_waitcnt vmcnt(0)");  // tail drain
    __builtin_amdgcn_sched_barrier(0);
    __builtin_amdgcn_s_barrier();
  }

  // ---- epilogue
#pragma unroll
  for (int qm = 0; qm < 2; ++qm)
#pragma unroll
    for (int m = 0; m < 4; ++m) {
      const int grow = m0 + qm * 128 + wm * 16 + m * 32 + lq * 4;
#pragma unroll
      for (int qn = 0; qn < 2; ++qn)
#pragma unroll
        for (int n = 0; n < 2; ++n) {
          const int gcol = n0 + qn * 128 + wn * 16 + n * 64 + lr;
          const f32x4 av = acc[qm * 4 + m][qn * 2 + n];
          if (OUT_MODE == 2) {
            const int which = gcol >> 10;
            const int h = (gcol >> 6) & 15;
            const int e = gcol & 63;
            const float* bp = (which == 0) ? bq : (which == 1) ? bk : bv;
            const float bvv = bp[gcol & 1023];
#pragma unroll
            for (int r = 0; r < 4; ++r) {
              const int row = grow + r;
              const int b_ = row >> 11, s_ = row & 2047;
              const size_t base = (size_t)((b_ << 4) + h) * 131072;
              const float val = av[r] + bvv;
              if (which == 0) {
                qo[base + (size_t)s_ * 64 + e] = f2bf(val);
              } else if (which == 1) {
                // K: fold softmax scale (1/8 * log2e) + XOR-octet swizzle
                const int o = e >> 3;
                const int pos = (((o ^ (s_ & 7)) << 3) | (e & 7));
                ko[base + (size_t)s_ * 64 + pos] = f2bf(val * 0.18033688011112f);
              } else {
                // V: attn layout [dh][2048], kappa-permuted + XOR-octet swz
                const int t = s_ >> 6, k64 = s_ & 63;
                const int kap = (k64 & 15) * 4 + (k64 >> 4);
                const int pos = (((kap >> 3) ^ (e & 7)) << 3) | (kap & 7);
                vo[base + (size_t)e * 2048 + t * 64 + pos] = f2bf(val);
              }
            }
          } else if (OUT_MODE == 3) {
#pragma unroll
            for (int r = 0; r < 4; ++r)
              ((unsigned short*)Cp)[(size_t)(grow + r) * ldc + gcol] =
                  f2bf(av[r]);
          } else {
            const float bvv = bias[gcol];
#pragma unroll
            for (int r = 0; r < 4; ++r) {
              float val = av[r] + bvv;
              if (RELU) val = fmaxf(val, 0.f);
              ((unsigned short*)Cp)[(size_t)(grow + r) * ldc + gcol] = f2bf(val);
            }
          }
        }
    }
}

// grids are 1 block/CU (128KB LDS); per-XCD rectangular tile chunks (T1).
__global__ __launch_bounds__(512, 2) void k_gemm_qkv(
    const unsigned short* __restrict__ xb, const unsigned short* __restrict__ Wt,
    const float* __restrict__ bq, const float* __restrict__ bk,
    const float* __restrict__ bv, unsigned short* __restrict__ qo,
    unsigned short* __restrict__ ko, unsigned short* __restrict__ vo) {
  // 192 blocks = 16 Mt x 12 Nt; 24/xcd as 4M x 6N rectangle
  const int bid = blockIdx.x;
  const int xcd = bid & 7, idx = bid >> 3;
  const int mt = (xcd >> 1) * 4 + idx / 6;
  const int nt = (xcd & 1) * 6 + idx % 6;
  gemm256_core<2, false>(xb, 1024, Wt, 1024, mt * 256, nt * 256, nullptr,
                         nullptr, 0, bq, bk, bv, qo, ko, vo);
}

__global__ __launch_bounds__(512, 2) void k_ffn1(
    const unsigned short* __restrict__ h1b, const unsigned short* __restrict__ W1t,
    const float* __restrict__ b1, unsigned short* __restrict__ f1) {
  // 256 blocks = 16 x 16; 32/xcd as 4M x 8N rectangle
  const int bid = blockIdx.x;
  const int xcd = bid & 7, idx = bid >> 3;
  const int mt = (xcd >> 1) * 4 + (idx >> 3);
  const int nt = (xcd & 1) * 8 + (idx & 7);
  gemm256_core<1, true>(h1b, 1024, W1t, 1024, mt * 256, nt * 256, b1, f1, 4096,
                        nullptr, nullptr, nullptr, nullptr, nullptr, nullptr);
}

// split-K=4: z covers k in [z*1024, z*1024+1024); partials at pbase + z*4M.
__global__ __launch_bounds__(512, 2) void k_ffn2(
    const unsigned short* __restrict__ f1, const unsigned short* __restrict__ W2t,
    unsigned short* __restrict__ pbase) {
  const int z = blockIdx.z;
  unsigned short* p = pbase + (size_t)z * 4194304;
  // 64 blocks/z = 16 Mt x 4 Nt; 8/xcd as 2M x 4N (2 A-panels + 4 B-panels = 3MB, L2-fit)
  const int bid = blockIdx.x;
  const int xcd = bid & 7, idx = bid >> 3;
  const int mt = xcd * 2 + (idx >> 2);
  const int nt = idx & 3;
  gemm256_core<3, false>(f1 + z * 1024, 4096, W2t + z * 1024, 4096, mt * 256,
                         nt * 256, nullptr, p, 1024, nullptr, nullptr, nullptr,
                         nullptr, nullptr, nullptr);
}

// ---------------- unified prep: x cvt + all weight transposes -------------
static DEVI void tr64(const float* __restrict__ s, int sld,
                      unsigned short* __restrict__ d, int dld) {
  __shared__ float t[64][65];
  const int tr = threadIdx.x >> 4;
  const int tc4 = (threadIdx.x & 15) * 4;
#pragma unroll
  for (int i = 0; i < 4; ++i) {
    f32x4 v = *(const f32x4*)(s + (size_t)(i * 16 + tr) * sld + tc4);
#pragma unroll
    for (int j = 0; j < 4; ++j) t[i * 16 + tr][tc4 + j] = v[j];
  }
  __syncthreads();
#pragma unroll
  for (int i = 0; i < 4; ++i) {
    const int c = i * 16 + tr;
    u16x4 pk;
#pragma unroll
    for (int j = 0; j < 4; ++j) pk[j] = f2bf(t[tc4 + j][c]);
    *(u16x4*)(d + (size_t)c * dld + tc4) = pk;
  }
}

// Flat grid 3840 blocks:
//   [0,1024)     x fp32 -> bf16 (16 elems/thread)
//   [1024,1792)  Wq/Wk/Wv [H][1024][64] -> wqkvt [3072][1024]
//   [1792,2816)  W1 [1024][4096]        -> w1t   [4096][1024]
//   [2816,3840)  W2 [4096][1024]        -> w2t   [1024][4096]
__global__ __launch_bounds__(256) void k_prep(
    const float* __restrict__ x, const float* __restrict__ Wq,
    const float* __restrict__ Wk, const float* __restrict__ Wv,
    const float* __restrict__ W1, const float* __restrict__ W2,
    unsigned short* __restrict__ xb, unsigned short* __restrict__ wqkvt,
    unsigned short* __restrict__ w1t, unsigned short* __restrict__ w2t) {
  const int bid = blockIdx.x;
  if (bid < 1024) {
    const size_t i0 = ((size_t)bid * 256 + threadIdx.x) * 16;
#pragma unroll
    for (int c = 0; c < 4; ++c) {
      f32x4 v = *(const f32x4*)(x + i0 + c * 4);
      u16x4 pk;
#pragma unroll
      for (int j = 0; j < 4; ++j) pk[j] = f2bf(v[j]);
      *(u16x4*)(xb + i0 + c * 4) = pk;
    }
  } else if (bid < 1792) {
    const int t = bid - 1024;
    const int bx = t & 15, by = t >> 4;  // by: 0..47
    const int which = by >> 4, h = by & 15;
    const float* W = (which == 0) ? Wq : (which == 1) ? Wk : Wv;
    const float* s = W + (size_t)h * 65536;
    unsigned short* d = wqkvt + (size_t)(which * 1024 + h * 64) * 1024;
    const int r0 = bx * 64;
    tr64(s + (size_t)r0 * 64, 64, d + r0, 1024);
  } else if (bid < 2816) {
    const int t = bid - 1792;
    const int bx = t & 15, by = t >> 4;  // R=1024, C=4096
    const int r0 = bx * 64, c0 = by * 64;
    tr64(W1 + (size_t)r0 * 4096 + c0, 4096, w1t + (size_t)c0 * 1024 + r0, 1024);
  } else {
    const int t = bid - 2816;
    const int bx = t & 63, by = t >> 6;  // R=4096, C=1024
    const int r0 = bx * 64, c0 = by * 64;
    tr64(W2 + (size_t)r0 * 1024 + c0, 1024, w2t + (size_t)c0 * 4096 + r0, 4096);
  }
}

// ---------------- flash attention (unmasked per reference bug) -------------
// No-max softmax (|score*scale| < ~4, exp2-safe). Scale pre-folded into K.
// 512 threads / 8 waves, 16 Q-rows per wave; async dbuf staging, 1 barrier.
// mha written bf16.
__global__ __launch_bounds__(512) void k_attn(
    const unsigned short* __restrict__ q, const unsigned short* __restrict__ ks,
    const unsigned short* __restrict__ vp, unsigned short* __restrict__ mha) {
  const int bid = blockIdx.x;
  const int bh = (bid & 7) * 4 + ((bid >> 3) >> 4);  // 4 bh per XCD (L2 locality)
  const int qt = (bid >> 3) & 15;
  const int b = bh >> 4, h = bh & 15;
  const int tid = threadIdx.x;
  const int w = tid >> 6, l = tid & 63;
  const int lr = l & 15, lq = l >> 4, l7 = lr & 7;

  __shared__ __align__(16) unsigned short Ks[2][64 * 64];  // swizzled [key][dh]
  __shared__ __align__(16) unsigned short Vt[2][64 * 64];  // swizzled [dh][kappa]
  __shared__ __align__(16) unsigned short Ps[8][16][72];   // per-wave P, padded

  const size_t bho = (size_t)bh * 131072;
  const int q0 = qt * 128 + w * 16;

  bf16x8 qf0, qf1;
  {
    const unsigned short* qp = q + bho + (size_t)(q0 + lr) * 64 + lq * 8;
    qf0 = *(const bf16x8*)qp;
    qf1 = *(const bf16x8*)(qp + 32);
  }

  f32x4 l_acc[4];
  f32x4 o[4];
#pragma unroll
  for (int i = 0; i < 4; ++i) {
    l_acc[i] = (f32x4){0.f, 0.f, 0.f, 0.f};
    o[i] = (f32x4){0.f, 0.f, 0.f, 0.f};
  }

  const unsigned short* kg = ks + bho;
  const unsigned short* vg = vp + bho;
  const int srow = l >> 3, scol = (l & 7) * 8;
  const int r0 = w * 8;

  async_ld16(kg + (size_t)(r0 + srow) * 64 + scol, &Ks[0][r0 * 64]);
  async_ld16(vg + (size_t)(r0 + srow) * 2048 + scol, &Vt[0][r0 * 64]);
  __syncthreads();

  for (int kt = 0; kt < 32; ++kt) {
    const int cur = kt & 1, nxt = cur ^ 1;
    if (kt + 1 < 32) {
      const int k1 = (kt + 1) * 64;
      async_ld16(kg + (size_t)(k1 + r0 + srow) * 64 + scol, &Ks[nxt][r0 * 64]);
      async_ld16(vg + (size_t)(r0 + srow) * 2048 + k1 + scol, &Vt[nxt][r0 * 64]);
    }

    bf16x8 kf[4][2];
#pragma unroll
    for (int ct = 0; ct < 4; ++ct)
#pragma unroll
      for (int hh = 0; hh < 2; ++hh)
        kf[ct][hh] = *(const bf16x8*)&Ks[cur][(ct * 16 + lr) * 64 +
                                             (((hh << 2) | lq) ^ l7) * 8];
    f32x4 s[4];
#pragma unroll
    for (int ct = 0; ct < 4; ++ct) {
      f32x4 t = {0.f, 0.f, 0.f, 0.f};
      t = mfma16x16x32(qf0, kf[ct][0], t);
      t = mfma16x16x32(qf1, kf[ct][1], t);
      s[ct] = t;
    }

#pragma unroll
    for (int r = 0; r < 4; ++r) {
      f32x4 pe;
#pragma unroll
      for (int ct = 0; ct < 4; ++ct)
        pe[ct] = __builtin_amdgcn_exp2f(s[ct][r]);
      l_acc[r] += pe;
      u16x4 pk;
#pragma unroll
      for (int ct = 0; ct < 4; ++ct) pk[ct] = f2bfh(pe[ct]);
      *(u16x4*)&Ps[w][lq * 4 + r][lr * 4] = pk;  // kappa = lr*4+ct
    }
    __asm__ volatile("" ::: "memory");

    bf16x8 vf[4][2];
#pragma unroll
    for (int dt = 0; dt < 4; ++dt)
#pragma unroll
      for (int hh = 0; hh < 2; ++hh)
        vf[dt][hh] = *(const bf16x8*)&Vt[cur][(dt * 16 + lr) * 64 +
                                             (((hh << 2) | lq) ^ l7) * 8];
    bf16x8 pf0 = *(const bf16x8*)&Ps[w][lr][lq * 8];
    bf16x8 pf1 = *(const bf16x8*)&Ps[w][lr][32 + lq * 8];
#pragma unroll
    for (int dt = 0; dt < 4; ++dt) {
      o[dt] = mfma16x16x32(pf0, vf[dt][0], o[dt]);
      o[dt] = mfma16x16x32(pf1, vf[dt][1], o[dt]);
    }
    __syncthreads();
  }

#pragma unroll
  for (int r = 0; r < 4; ++r) {
    f32x4 la = l_acc[r];
    float sd = la[0] + la[1] + la[2] + la[3];
    sd += __shfl_xor(sd, 1);
    sd += __shfl_xor(sd, 2);
    sd += __shfl_xor(sd, 4);
    sd += __shfl_xor(sd, 8);
    const float inv = 1.f / sd;
    unsigned short* op =
        mha + ((size_t)b * 2048 + q0 + lq * 4 + r) * 1024 + h * 64 + lr;
    op[0] = f2bfh(o[0][r] * inv);
    op[16] = f2bfh(o[1][r] * inv);
    op[32] = f2bfh(o[2][r] * inv);
    op[48] = f2bfh(o[3][r] * inv);
  }
}

// ---------------- fused residual-add + LayerNorm -> bf16 ----------------
// a fp32 (x), b bf16 (mha).
__global__ __launch_bounds__(256) void k_add_ln(const float* __restrict__ a,
                                                const unsigned short* __restrict__ b,
                                                const float* __restrict__ g,
                                                const float* __restrict__ be,
                                                unsigned short* __restrict__ outb) {
  const int row = blockIdx.x;
  const int tid = threadIdx.x;
  const size_t base = (size_t)row * 1024 + tid * 4;
  f32x4 va = *(const f32x4*)(a + base);
  u16x4 ub = *(const u16x4*)(b + base);
  f32x4 xx;
  float s = 0.f, q = 0.f;
#pragma unroll
  for (int i = 0; i < 4; ++i) {
    xx[i] = va[i] + bf2f(ub[i]);
    s += xx[i];
    q += xx[i] * xx[i];
  }
#pragma unroll
  for (int off = 1; off < 64; off <<= 1) {
    s += __shfl_xor(s, off);
    q += __shfl_xor(q, off);
  }
  __shared__ float ss[4], qs[4];
  const int w = tid >> 6;
  if ((tid & 63) == 0) { ss[w] = s; qs[w] = q; }
  __syncthreads();
  s = ss[0] + ss[1] + ss[2] + ss[3];
  q = qs[0] + qs[1] + qs[2] + qs[3];
  const float mean = s * (1.f / 1024.f);
  const float var = q * (1.f / 1024.f) - mean * mean;
  const float rstd = rsqrtf(var + 1e-5f);
  f32x4 vg = *(const f32x4*)(g + tid * 4);
  f32x4 vbe = *(const f32x4*)(be + tid * 4);
  u16x4 pk;
#pragma unroll
  for (int i = 0; i < 4; ++i)
    pk[i] = f2bf((xx[i] - mean) * rstd * vg[i] + vbe[i]);
  *(u16x4*)(outb + base) = pk;
}

// out = LN(h1b + p0..p3 + b2): ffn2 split-K=4 partials + bias + LN (fp32 out).
__global__ __launch_bounds__(256) void k_add_ln4(
    const unsigned short* __restrict__ h1b, const unsigned short* __restrict__ pb,
    const float* __restrict__ cb, const float* __restrict__ g,
    const float* __restrict__ be, float* __restrict__ out) {
  const int row = blockIdx.x;
  const int tid = threadIdx.x;
  const size_t base = (size_t)row * 1024 + tid * 4;
  u16x4 uh = *(const u16x4*)(h1b + base);
  u16x4 up[4];
#pragma unroll
  for (int z = 0; z < 4; ++z)
    up[z] = *(const u16x4*)(pb + base + (size_t)z * 4194304);
  f32x4 vcb = *(const f32x4*)(cb + tid * 4);
  f32x4 xx;
  float s = 0.f, q = 0.f;
#pragma unroll
  for (int i = 0; i < 4; ++i) {
    float v = bf2f(uh[i]) + vcb[i];
#pragma unroll
    for (int z = 0; z < 4; ++z) v += bf2f(up[z][i]);
    xx[i] = v;
    s += v;
    q += v * v;
  }
#pragma unroll
  for (int off = 1; off < 64; off <<= 1) {
    s += __shfl_xor(s, off);
    q += __shfl_xor(q, off);
  }
  __shared__ float ss[4], qs[4];
  const int w = tid >> 6;
  if ((tid & 63) == 0) { ss[w] = s; qs[w] = q; }
  __syncthreads();
  s = ss[0] + ss[1] + ss[2] + ss[3];
  q = qs[0] + qs[1] + qs[2] + qs[3];
  const float mean = s * (1.f / 1024.f);
  const float var = q * (1.f / 1024.f) - mean * mean;
  const float rstd = rsqrtf(var + 1e-5f);
  f32x4 vg = *(const f32x4*)(g + tid * 4);
  f32x4 vbe = *(const f32x4*)(be + tid * 4);
  f32x4 ov;
#pragma unroll
  for (int i = 0; i < 4; ++i) ov[i] = (xx[i] - mean) * rstd * vg[i] + vbe[i];
  *(f32x4*)(out + base) = ov;
}

// ---------------- host launcher ----------------
extern "C" void kernel_launch(void* const* d_in, const int* in_sizes, int n_in,
                              void* d_out, int out_size, void* d_ws,
                              size_t ws_size, hipStream_t stream) {
  const float* x = (const float*)d_in[0];
  // d_in[1] attention_mask: discarded by reference (typo bug) -> unused
  const float* Wq = (const float*)d_in[2];
  const float* bq = (const float*)d_in[3];
  const float* Wk = (const float*)d_in[4];
  const float* bk = (const float*)d_in[5];
  const float* Wv = (const float*)d_in[6];
  const float* bv = (const float*)d_in[7];
  const float* lg = (const float*)d_in[8];
  const float* lb = (const float*)d_in[9];
  const float* W1 = (const float*)d_in[10];
  const float* b1 = (const float*)d_in[11];
  const float* W2 = (const float*)d_in[12];
  const float* b2 = (const float*)d_in[13];

  char* ws = (char*)d_ws;
  const size_t MB = 1024 * 1024;
  // liveness-overlapped plan (peak 94 MB):
  unsigned short* qb = (unsigned short*)(ws + 0);          // 8MB [qkv -> attn]
  unsigned short* kb = (unsigned short*)(ws + 8 * MB);     // 8MB [qkv -> attn]
  unsigned short* vp = (unsigned short*)(ws + 16 * MB);    // 8MB [qkv -> attn]
  unsigned short* f1 = (unsigned short*)(ws + 0);          // 32MB [ffn1 -> ffn2]
  unsigned short* xb = (unsigned short*)(ws + 32 * MB);    // 8MB [prep -> qkv]
  unsigned short* pb = (unsigned short*)(ws + 32 * MB);    // 32MB [ffn2 -> ln4]
  unsigned short* mha = (unsigned short*)(ws + 40 * MB);   // 8MB bf16 [attn -> ln1]
  unsigned short* h1b = (unsigned short*)(ws + 64 * MB);   // 8MB [ln1 -> ffn1,ln4]
  unsigned short* wqkvt = (unsigned short*)(ws + 72 * MB); // 6MB [prep -> qkv]
  unsigned short* w1t = (unsigned short*)(ws + 78 * MB);   // 8MB [prep -> ffn1]
  unsigned short* w2t = (unsigned short*)(ws + 86 * MB);   // 8MB [prep -> ffn2]

  k_prep<<<dim3(3840), 256, 0, stream>>>(x, Wq, Wk, Wv, W1, W2, xb, wqkvt, w1t,
                                         w2t);
  k_gemm_qkv<<<dim3(192), 512, 0, stream>>>(xb, wqkvt, bq, bk, bv, qb, kb, vp);
  k_attn<<<dim3(512), 512, 0, stream>>>(qb, kb, vp, mha);
  k_add_ln<<<dim3(4096), 256, 0, stream>>>(x, mha, lg, lb, h1b);
  k_ffn1<<<dim3(256), 512, 0, stream>>>(h1b, w1t, b1, f1);
  k_ffn2<<<dim3(64, 1, 4), 512, 0, stream>>>(f1, w2t, pb);
  k_add_ln4<<<dim3(4096), 256, 0, stream>>>(h1b, pb, b2, lg, lb, (float*)d_out);
}